// Round 12
// baseline (223.540 us; speedup 1.0000x reference)
//
#include <hip/hip_runtime.h>

#define N_NODES 100000
#define N_HEDGES 25000
#define N_EDGES 1000000
#define NG 64
#define HD 64

// binned CSR build params
#define EB_SH 8
#define EB_NB 98
#define EB_CAP 12000
#define NB_SH 9
#define NB_NB 196
#define NB_CAP 6200
#define TILE 4096
#define TPS 245
#define ENC_F4 ((N_NODES + N_HEDGES) * 16)

typedef __attribute__((ext_vector_type(4))) float f4;
typedef __attribute__((ext_vector_type(4))) unsigned short us4;
typedef __attribute__((ext_vector_type(8))) unsigned short us8;
typedef __attribute__((ext_vector_type(8))) short s8b;   // MFMA bf16 A/B fragment

__device__ __forceinline__ unsigned short f2bf(float f) {
    unsigned int u = __float_as_uint(f);
    unsigned int r = (u + 0x7FFFu + ((u >> 16) & 1u)) >> 16;  // RNE
    return (unsigned short)r;
}
__device__ __forceinline__ float bf2f(unsigned short h) {
    return __uint_as_float((unsigned int)h << 16);
}
__device__ __forceinline__ us4 f4_to_bf4(f4 v) {
    us4 h;
    h[0] = f2bf(v[0]); h[1] = f2bf(v[1]); h[2] = f2bf(v[2]); h[3] = f2bf(v[3]);
    return h;
}

// ---------------- prep: W->Wt bf16 transpose (blocks 0-3) + zero (rest) ----------------
__global__ __launch_bounds__(256) void prep(
    const float* __restrict__ W1lE, const float* __restrict__ W1rE,
    const float* __restrict__ W1lN, const float* __restrict__ W1rN,
    const float* __restrict__ W2lE, const float* __restrict__ W2rE,
    const float* __restrict__ W2lN, const float* __restrict__ W2rN,
    unsigned short* __restrict__ WtH, int* __restrict__ zbase, int zn) {
    int b = blockIdx.x, t = threadIdx.x;
    if (b < 4) {
        const float *Wl, *Wr;
        switch (b) {
            case 0: Wl = W1lE; Wr = W1rE; break;
            case 1: Wl = W1lN; Wr = W1rN; break;
            case 2: Wl = W2lE; Wr = W2rE; break;
            default: Wl = W2lN; Wr = W2rN; break;
        }
        unsigned short* o = WtH + b * 8192;
        for (int idx = t; idx < 8192; idx += 256) {
            int c = idx >> 7, k = idx & 127;
            float v = (k < 64) ? Wl[k * 64 + c] : Wr[(k - 64) * 64 + c];
            o[c * 128 + k] = f2bf(v);  // Wt[col][k]: B^T layout
        }
    } else {
        int i = (b - 4) * 256 + t;
        if (i < zn) zbase[i] = 0;
    }
}

// ---------------- pass 1: LDS-binned scatter + fused encoder (row-major bf16 out) ----------------
__global__ __launch_bounds__(256) void bin_encode(
    const int* __restrict__ n2e_src, const int* __restrict__ n2e_dst,
    const int* __restrict__ e2n_src, const int* __restrict__ e2n_dst,
    int* __restrict__ binE, int* __restrict__ binN,
    int* __restrict__ gcntE, int* __restrict__ gcntN,
    const float* __restrict__ node_x, const float* __restrict__ edge_x,
    const float* __restrict__ Wn, const float* __restrict__ bn,
    const float* __restrict__ We, const float* __restrict__ be,
    unsigned short* __restrict__ xnH, unsigned short* __restrict__ xeH) {
    __shared__ int pairsL[TILE];
    __shared__ int hist[256], scanv[256], start[256], curs[256], gbase[256];
    int t = threadIdx.x;
    if ((int)blockIdx.x >= 2 * TPS) {
        int i4 = ((int)blockIdx.x - 2 * TPS) * 256 + t;
        if (i4 < N_NODES * 16) {
            int row = i4 >> 4, fq = i4 & 15;
            f4 wn = *(const f4*)(Wn + fq * 4);
            f4 bnv = *(const f4*)(bn + fq * 4);
            float xv = node_x[row];
            f4 v;
#pragma unroll
            for (int c = 0; c < 4; c++) v[c] = fmaxf(xv * wn[c] + bnv[c], 0.f);
            *(us4*)(xnH + (long)i4 * 4) = f4_to_bf4(v);
        } else if (i4 < ENC_F4) {
            int j = i4 - N_NODES * 16;
            int row = j >> 4, fq = j & 15;
            f4 w0 = *(const f4*)(We + fq * 4);
            f4 w1 = *(const f4*)(We + HD + fq * 4);
            f4 bev = *(const f4*)(be + fq * 4);
            float x0 = edge_x[2 * row], x1 = edge_x[2 * row + 1];
            f4 v;
#pragma unroll
            for (int c = 0; c < 4; c++) v[c] = fmaxf(x0 * w0[c] + x1 * w1[c] + bev[c], 0.f);
            *(us4*)(xeH + (long)j * 4) = f4_to_bf4(v);
        }
        return;
    }
    int side = (int)blockIdx.x >= TPS;
    int lb = blockIdx.x - (side ? TPS : 0);
    const int* dsts = side ? e2n_dst : n2e_dst;
    const int* srcs = side ? e2n_src : n2e_src;
    int NB = side ? NB_NB : EB_NB;
    int SH = side ? NB_SH : EB_SH;
    int CAP = side ? NB_CAP : EB_CAP;
    int* bins = side ? binN : binE;
    int* gcnt = side ? gcntN : gcntE;
    int base = lb * TILE;

    hist[t] = 0;
    __syncthreads();

    int pair[16], buck[16];
#pragma unroll
    for (int k = 0; k < 16; k++) {
        int e = base + k * 256 + t;
        if (e < N_EDGES) {
            int d = dsts[e];
            int s = srcs[e];
            buck[k] = d >> SH;
            pair[k] = ((d & ((1 << SH) - 1)) << 17) | s;
            atomicAdd(&hist[buck[k]], 1);
        } else buck[k] = -1;
    }
    __syncthreads();
    int v = hist[t];
    scanv[t] = v;
    __syncthreads();
    for (int o = 1; o < 256; o <<= 1) {
        int x = (t >= o) ? scanv[t - o] : 0;
        __syncthreads();
        scanv[t] += x;
        __syncthreads();
    }
    start[t] = scanv[t] - v;
    curs[t] = scanv[t] - v;
    if (t < NB && v > 0) gbase[t] = t * CAP + atomicAdd(&gcnt[t], v);
    __syncthreads();
    int total = scanv[255];
#pragma unroll
    for (int k = 0; k < 16; k++) {
        if (buck[k] >= 0) {
            int slot = atomicAdd(&curs[buck[k]], 1);
            pairsL[slot] = pair[k];
        }
    }
    __syncthreads();
    for (int i = t; i < total; i += 256) {
        int lo = 0, hi = NB - 1;
        while (lo < hi) { int mid = (lo + hi + 1) >> 1; if (start[mid] <= i) lo = mid; else hi = mid - 1; }
        bins[gbase[lo] + (i - start[lo])] = pairsL[i];
    }
}

// ---------------- pass 2: per-bucket fine CSR fill (E-side u32 src, N-side u16 src) ----------------
__global__ __launch_bounds__(512) void fine_fill(
    const int* __restrict__ binE, const int* __restrict__ binN,
    const int* __restrict__ gcntE, const int* __restrict__ gcntN,
    int* __restrict__ off, int* __restrict__ deg,
    int* __restrict__ srtE, unsigned short* __restrict__ srtN) {
    __shared__ int hist[512], scanv[512];
    int t = threadIdx.x;
    int side = (int)blockIdx.x >= EB_NB;
    int b = blockIdx.x - (side ? EB_NB : 0);
    int NROWS = side ? 512 : 256;
    int CAP = side ? NB_CAP : EB_CAP;
    const int* bins = (side ? binN : binE) + (long)b * CAP;
    int cnt_b = (side ? gcntN : gcntE)[b];
    int rowbase = side ? (N_HEDGES + b * 512) : b * 256;
    int nrows = (side ? N_NODES : N_HEDGES) - (side ? b * 512 : b * 256);
    if (nrows > NROWS) nrows = NROWS;
    int* srtEb = srtE + (long)b * CAP;
    unsigned short* srtNb = srtN + (long)b * CAP;

    hist[t] = 0;
    __syncthreads();
    for (int i = t; i < cnt_b; i += 512) atomicAdd(&hist[bins[i] >> 17], 1);
    __syncthreads();
    int v = hist[t];
    scanv[t] = v;
    __syncthreads();
    for (int o = 1; o < 512; o <<= 1) {
        int x = (t >= o) ? scanv[t - o] : 0;
        __syncthreads();
        scanv[t] += x;
        __syncthreads();
    }
    int excl = scanv[t] - v;
    if (t < nrows) { off[rowbase + t] = b * CAP + excl; deg[rowbase + t] = v; }
    scanv[t] = excl;
    __syncthreads();
    for (int i = t; i < cnt_b; i += 512) {
        int p = bins[i];
        int pos = atomicAdd(&scanv[p >> 17], 1);
        if (side) srtNb[pos] = (unsigned short)(p & 0x1FFFF);  // hyperedge ids < 25000
        else srtEb[pos] = p & 0x1FFFF;                         // node ids < 100000
    }
}

// ---------------- fused SAGE layer: gather (round-9 inner loop) + MFMA combine ----------------
// Block = 64 dst rows, 4 waves. LDS: sA agg tile [64][72] + sW Wt [64][136] = 26.6 KB
// (6 blocks/CU). xdst half of the A-operand is prefetched into per-lane fragment
// registers BEFORE the gather phase (latency hidden under gather).
__global__ __launch_bounds__(256) void sage_fused(
    const unsigned short* __restrict__ xnH, const unsigned short* __restrict__ xeH,
    const int* __restrict__ off, const int* __restrict__ deg,
    const int* __restrict__ srtE, const unsigned short* __restrict__ srtN,
    const unsigned short* __restrict__ WtE, const float* __restrict__ blE,
    const unsigned short* __restrict__ WtN, const float* __restrict__ blN,
    unsigned short* __restrict__ outEH, unsigned short* __restrict__ outNH, int gbE) {
    __shared__ unsigned short sA[64][72];   // agg tile (bf16), pitch 144B -> bank-rotated
    __shared__ unsigned short sW[64][136];  // Wt tile, pitch 272B
    int t = threadIdx.x;
    int lane = t & 63, wv = t >> 6;
    bool eSide = (int)blockIdx.x < gbE;
    const unsigned short* xsrc = eSide ? xnH : xeH;
    const unsigned short* xdstH = eSide ? xeH : xnH;
    const unsigned short* Wt = eSide ? WtE : WtN;
    const float* bl = eSide ? blE : blN;
    unsigned short* outH = eSide ? outEH : outNH;
    int rows = eSide ? N_HEDGES : N_NODES;
    int row0 = (eSide ? (int)blockIdx.x : (int)blockIdx.x - gbE) * 64;
    int rbase = eSide ? 0 : N_HEDGES;

    int m0 = wv * 16;
    int l15 = lane & 15, quad = lane >> 4;

    // prefetch xdst MFMA fragments (K = 64..127) into registers; hides under gather
    s8b xf[2];
    {
        int grf = row0 + m0 + l15;
#pragma unroll
        for (int kb2 = 0; kb2 < 2; kb2++) {
            if (grf < rows)
                xf[kb2] = *(const s8b*)(xdstH + (long)grf * HD + kb2 * 32 + quad * 8);
            else
                xf[kb2] = (s8b){0, 0, 0, 0, 0, 0, 0, 0};
        }
    }

    // stage Wt into LDS
#pragma unroll
    for (int q = 0; q < 4; q++) {
        int idx = q * 256 + t;
        int c = idx >> 4, ch = idx & 15;
        *(us8*)&sW[c][ch * 8] = *(const us8*)(Wt + c * 128 + ch * 8);
    }

    // gather phase: wave wv -> rows wv*16 .. +15 (round-9 inner loop: 16 lanes x us4, 4 edges/instr)
    int esub = lane >> 4;   // 0..3 edge sublane
    int fq = lane & 15;     // f4 chunk
    for (int i = 0; i < 16; i++) {
        int rr = wv * 16 + i;
        int gr = row0 + rr;
        if (gr >= rows) break;
        int lo = off[rbase + gr];
        int dg = deg[rbase + gr];
        f4 a0 = {0.f, 0.f, 0.f, 0.f}, a1 = a0;
        for (int j0 = 0; j0 < dg; j0 += 64) {
            int chunk = dg - j0;
            if (chunk > 64) chunk = 64;
            int idv;
            if (eSide) idv = (j0 + lane < dg) ? srtE[lo + j0 + lane] : 0;
            else idv = (j0 + lane < dg) ? (int)srtN[lo + j0 + lane] : 0;
            int jj = 0;
            for (; jj + 8 <= chunk; jj += 8) {
                int s0 = __shfl(idv, jj + esub);
                int s1 = __shfl(idv, jj + 4 + esub);
                us4 h0 = ((const us4*)(xsrc + (long)s0 * HD))[fq];
                us4 h1 = ((const us4*)(xsrc + (long)s1 * HD))[fq];
#pragma unroll
                for (int c = 0; c < 4; c++) { a0[c] += bf2f(h0[c]); a1[c] += bf2f(h1[c]); }
            }
            for (; jj < chunk; jj += 4) {
                int e = jj + esub;
                int s = __shfl(idv, e & 63);
                us4 h = ((const us4*)(xsrc + (long)s * HD))[fq];
                if (e < chunk) {
#pragma unroll
                    for (int c = 0; c < 4; c++) a0[c] += bf2f(h[c]);
                }
            }
        }
        f4 acc = a0 + a1;
#pragma unroll
        for (int c = 0; c < 4; c++) {
            acc[c] += __shfl_xor(acc[c], 16);
            acc[c] += __shfl_xor(acc[c], 32);
        }
        if (lane < 16) {
            float invd = 1.f / (float)(dg > 1 ? dg : 1);
            *(us4*)&sA[rr][fq * 4] = f4_to_bf4(acc * invd);
        }
    }
    __syncthreads();

    // MFMA phase: acc = [agg | xdst] @ Wt + bl  (K=128: kb 0,1 from sA; kb 2,3 from xf regs)
    f4 acc[4];
#pragma unroll
    for (int ct = 0; ct < 4; ct++) {
        float b = bl[ct * 16 + l15];
        acc[ct] = (f4){b, b, b, b};
    }
#pragma unroll
    for (int kb = 0; kb < 4; kb++) {
        s8b a;
        if (kb < 2) a = *(const s8b*)&sA[m0 + l15][kb * 32 + quad * 8];
        else a = xf[kb - 2];
#pragma unroll
        for (int ct = 0; ct < 4; ct++) {
            s8b bfr = *(const s8b*)&sW[ct * 16 + l15][kb * 32 + quad * 8];
            acc[ct] = __builtin_amdgcn_mfma_f32_16x16x32_bf16(a, bfr, acc[ct], 0, 0, 0);
        }
    }
#pragma unroll
    for (int ct = 0; ct < 4; ct++) {
#pragma unroll
        for (int r = 0; r < 4; r++) {
            int gr = row0 + m0 + quad * 4 + r;
            if (gr < rows) outH[(long)gr * HD + ct * 16 + l15] = f2bf(fmaxf(acc[ct][r], 0.f));
        }
    }
}

// ---------------- parallel pooling from bf16 feats ----------------
__device__ __forceinline__ int lower_bound_dev(const int* arr, int n, int key) {
    int lo = 0, hi = n;
    while (lo < hi) { int mid = (lo + hi) >> 1; if (arr[mid] < key) lo = mid + 1; else hi = mid; }
    return lo;
}

#define PB_N 8
#define PB_E 2
__global__ __launch_bounds__(256) void pool_bf(
    const unsigned short* __restrict__ xnH, const unsigned short* __restrict__ xeH,
    const int* __restrict__ node_batch, const int* __restrict__ edge_batch,
    float* __restrict__ poolN, float* __restrict__ poolE) {
    __shared__ float sp[4][64];
    int b = blockIdx.x;
    const unsigned short* x; const int* batch; float* pool; int n, g, part, P;
    if (b < NG * PB_N) { x = xnH; batch = node_batch; pool = poolN; n = N_NODES; g = b / PB_N; part = b % PB_N; P = PB_N; }
    else { b -= NG * PB_N; x = xeH; batch = edge_batch; pool = poolE; n = N_HEDGES; g = b / PB_E; part = b % PB_E; P = PB_E; }
    int s = lower_bound_dev(batch, n, g);
    int e = lower_bound_dev(batch, n, g + 1);
    int len = e - s;
    int start = s + (int)(((long)len * part) / P);
    int end = s + (int)(((long)len * (part + 1)) / P);
    int lane = threadIdx.x & 63, w = threadIdx.x >> 6;
    int fq = lane & 7, sub = lane >> 3;
    f4 a0 = {0.f, 0.f, 0.f, 0.f}, a1 = a0;
    for (int r = start + w * 8 + sub; r < end; r += 32) {
        us8 h = *(const us8*)(x + (long)r * HD + fq * 8);
#pragma unroll
        for (int c = 0; c < 4; c++) { a0[c] += bf2f(h[c]); a1[c] += bf2f(h[c + 4]); }
    }
#pragma unroll
    for (int c = 0; c < 4; c++) {
        a0[c] += __shfl_xor(a0[c], 8);  a1[c] += __shfl_xor(a1[c], 8);
        a0[c] += __shfl_xor(a0[c], 16); a1[c] += __shfl_xor(a1[c], 16);
        a0[c] += __shfl_xor(a0[c], 32); a1[c] += __shfl_xor(a1[c], 32);
    }
    if (lane < 8) {
        *(f4*)&sp[w][fq * 8] = a0;
        *(f4*)&sp[w][fq * 8 + 4] = a1;
    }
    __syncthreads();
    if (threadIdx.x < 64) {
        int tt = threadIdx.x;
        float v = sp[0][tt] + sp[1][tt] + sp[2][tt] + sp[3][tt];
        if (v != 0.f) atomicAdd(&pool[g * HD + tt], v);
    }
}

// ---------------- final readout (one block per graph) ----------------
__global__ __launch_bounds__(64) void final_readout(
    const float* __restrict__ poolN, const float* __restrict__ poolE,
    const int* __restrict__ node_batch, const int* __restrict__ edge_batch,
    const float* __restrict__ Wout, const float* __restrict__ bout,
    float* __restrict__ out) {
    __shared__ float inv[2];
    int g = blockIdx.x, t = threadIdx.x;
    if (t < 2) {
        const int* arr = t ? edge_batch : node_batch;
        int n = t ? N_HEDGES : N_NODES;
        int lo = lower_bound_dev(arr, n, g);
        int hi = lower_bound_dev(arr, n, g + 1);
        int c = hi - lo;
        inv[t] = 1.f / (float)(c > 1 ? c : 1);
    }
    __syncthreads();
    if (t < 32) {
        float iN = inv[0], iE = inv[1];
        float s = bout[t];
#pragma unroll 8
        for (int k = 0; k < HD; k++)
            s += poolN[g * HD + k] * iN * Wout[k * 32 + t]
               + poolE[g * HD + k] * iE * Wout[(HD + k) * 32 + t];
        out[g * 32 + t] = s;
    }
}

extern "C" void kernel_launch(void* const* d_in, const int* in_sizes, int n_in,
                              void* d_out, int out_size, void* d_ws, size_t ws_size,
                              hipStream_t stream) {
    const float* node_x = (const float*)d_in[0];
    const float* edge_x = (const float*)d_in[1];
    const int* n2e_src = (const int*)d_in[2];
    const int* n2e_dst = (const int*)d_in[3];
    const int* e2n_src = (const int*)d_in[4];
    const int* e2n_dst = (const int*)d_in[5];
    const int* node_batch = (const int*)d_in[6];
    const int* edge_batch = (const int*)d_in[7];
    const float* Wn = (const float*)d_in[8];
    const float* bn = (const float*)d_in[9];
    const float* We = (const float*)d_in[10];
    const float* be = (const float*)d_in[11];
    const float* W1l_n2e = (const float*)d_in[12];
    const float* b1l_n2e = (const float*)d_in[13];
    const float* W1r_n2e = (const float*)d_in[14];
    const float* W1l_e2n = (const float*)d_in[15];
    const float* b1l_e2n = (const float*)d_in[16];
    const float* W1r_e2n = (const float*)d_in[17];
    const float* W2l_n2e = (const float*)d_in[18];
    const float* b2l_n2e = (const float*)d_in[19];
    const float* W2r_n2e = (const float*)d_in[20];
    const float* W2l_e2n = (const float*)d_in[21];
    const float* b2l_e2n = (const float*)d_in[22];
    const float* W2r_e2n = (const float*)d_in[23];
    const float* Wout = (const float*)d_in[24];
    const float* bout = (const float*)d_in[25];
    float* out = (float*)d_out;

    // ---- workspace layout (row-major bf16 features; agg arrays eliminated) ----
    unsigned short* AH0 = (unsigned short*)d_ws;        // 6.4M us: xn bf16 -> xn2
    unsigned short* BH0 = AH0 + N_NODES * HD;           // 1.6M: xe -> xe2
    unsigned short* AH1 = BH0 + N_HEDGES * HD;          // 6.4M: xn1
    unsigned short* BH1 = AH1 + N_NODES * HD;           // 1.6M: xe1
    unsigned short* WtH = BH1 + N_HEDGES * HD;          // 32768 (4 x [64][128])
    float* poolN = (float*)(WtH + 4 * 8192);            // 4096
    float* poolE = poolN + NG * HD;                     // 4096
    int* gcntE = (int*)(poolE + NG * HD);               // 98
    int* gcntN = gcntE + EB_NB;                         // 196
    int* off = gcntN + NB_NB;                           // 125000
    int* deg = off + (N_HEDGES + N_NODES);              // 125000
    int* binE = deg + (N_HEDGES + N_NODES);             // 1,176,000
    int* binN = binE + EB_NB * EB_CAP;                  // 1,215,200
    int* srtE = binN + NB_NB * NB_CAP;                  // 1,176,000 u32
    unsigned short* srtN = (unsigned short*)(srtE + EB_NB * EB_CAP);  // 1,215,200 u16

    const int Bt = 256;

    // 1) prep: Wt conversion + zero pools/cursors (contiguous: poolN..gcntN)
    int zn = 2 * NG * HD + EB_NB + NB_NB;
    prep<<<4 + (zn + Bt - 1) / Bt, Bt, 0, stream>>>(
        W1l_n2e, W1r_n2e, W1l_e2n, W1r_e2n,
        W2l_n2e, W2r_n2e, W2l_e2n, W2r_e2n,
        WtH, (int*)poolN, zn);

    // 2) binning + encoder
    int encBlocks = (ENC_F4 + Bt - 1) / Bt;
    bin_encode<<<2 * TPS + encBlocks, Bt, 0, stream>>>(
        n2e_src, n2e_dst, e2n_src, e2n_dst, binE, binN, gcntE, gcntN,
        node_x, edge_x, Wn, bn, We, be, AH0, BH0);

    // 3) fine CSR fill
    fine_fill<<<EB_NB + NB_NB, 512, 0, stream>>>(binE, binN, gcntE, gcntN,
                                                 off, deg, srtE, srtN);

    int gbE = (N_HEDGES + 63) / 64;  // 391
    int gbN = (N_NODES + 63) / 64;   // 1563
    int gridC = gbE + gbN;           // 1954

    // 4) layer 1 (fused gather+combine)
    sage_fused<<<gridC, Bt, 0, stream>>>(AH0, BH0, off, deg, srtE, srtN,
                                         WtH, b1l_n2e, WtH + 8192, b1l_e2n,
                                         BH1, AH1, gbE);

    // 5) layer 2
    sage_fused<<<gridC, Bt, 0, stream>>>(AH1, BH1, off, deg, srtE, srtN,
                                         WtH + 16384, b2l_n2e, WtH + 24576, b2l_e2n,
                                         BH0, AH0, gbE);

    // 6) pooling
    pool_bf<<<NG * PB_N + NG * PB_E, Bt, 0, stream>>>(AH0, BH0, node_batch, edge_batch, poolN, poolE);

    // 7) readout
    final_readout<<<NG, 64, 0, stream>>>(poolN, poolE, node_batch, edge_batch, Wout, bout, out);
}

// Round 13
// 184.052 us; speedup vs baseline: 1.2145x; 1.2145x over previous
//
#include <hip/hip_runtime.h>

#define N_NODES 100000
#define N_HEDGES 25000
#define N_EDGES 1000000
#define NG 64
#define HD 64

// binned CSR build params
#define EB_SH 8
#define EB_NB 98
#define EB_CAP 12000
#define NB_SH 9
#define NB_NB 196
#define NB_CAP 6200
#define TILE 4096
#define TPS 245
#define ENC_F4 ((N_NODES + N_HEDGES) * 16)

typedef __attribute__((ext_vector_type(4))) float f4;
typedef __attribute__((ext_vector_type(4))) _Float16 h4;
typedef __attribute__((ext_vector_type(8))) _Float16 h8;
typedef __attribute__((ext_vector_type(2))) int i2;

__device__ __forceinline__ h4 f4_to_h4(f4 v) {
    h4 o;
    o[0] = (_Float16)v[0]; o[1] = (_Float16)v[1];
    o[2] = (_Float16)v[2]; o[3] = (_Float16)v[3];
    return o;
}

// ---------------- prep: W->Wt f16 transpose (blocks 0-3) + zero (rest) ----------------
__global__ __launch_bounds__(256) void prep(
    const float* __restrict__ W1lE, const float* __restrict__ W1rE,
    const float* __restrict__ W1lN, const float* __restrict__ W1rN,
    const float* __restrict__ W2lE, const float* __restrict__ W2rE,
    const float* __restrict__ W2lN, const float* __restrict__ W2rN,
    _Float16* __restrict__ WtH, int* __restrict__ zbase, int zn) {
    int b = blockIdx.x, t = threadIdx.x;
    if (b < 4) {
        const float *Wl, *Wr;
        switch (b) {
            case 0: Wl = W1lE; Wr = W1rE; break;
            case 1: Wl = W1lN; Wr = W1rN; break;
            case 2: Wl = W2lE; Wr = W2rE; break;
            default: Wl = W2lN; Wr = W2rN; break;
        }
        _Float16* o = WtH + b * 8192;
        for (int idx = t; idx < 8192; idx += 256) {
            int c = idx >> 7, k = idx & 127;
            float v = (k < 64) ? Wl[k * 64 + c] : Wr[(k - 64) * 64 + c];
            o[c * 128 + k] = (_Float16)v;  // Wt[col][k]: B^T layout
        }
    } else {
        int i = (b - 4) * 256 + t;
        if (i < zn) zbase[i] = 0;
    }
}

// ---------------- pass 1: LDS-binned scatter + fused encoder (row-major f16 out) ----------------
__global__ __launch_bounds__(256) void bin_encode(
    const int* __restrict__ n2e_src, const int* __restrict__ n2e_dst,
    const int* __restrict__ e2n_src, const int* __restrict__ e2n_dst,
    int* __restrict__ binE, int* __restrict__ binN,
    int* __restrict__ gcntE, int* __restrict__ gcntN,
    const float* __restrict__ node_x, const float* __restrict__ edge_x,
    const float* __restrict__ Wn, const float* __restrict__ bn,
    const float* __restrict__ We, const float* __restrict__ be,
    _Float16* __restrict__ xnH, _Float16* __restrict__ xeH) {
    __shared__ int pairsL[TILE];
    __shared__ int hist[256], scanv[256], start[256], curs[256], gbase[256];
    int t = threadIdx.x;
    if ((int)blockIdx.x >= 2 * TPS) {
        int i4 = ((int)blockIdx.x - 2 * TPS) * 256 + t;
        if (i4 < N_NODES * 16) {
            int row = i4 >> 4, fq = i4 & 15;
            f4 wn = *(const f4*)(Wn + fq * 4);
            f4 bnv = *(const f4*)(bn + fq * 4);
            float xv = node_x[row];
            f4 v;
#pragma unroll
            for (int c = 0; c < 4; c++) v[c] = fmaxf(xv * wn[c] + bnv[c], 0.f);
            *(h4*)(xnH + (long)i4 * 4) = f4_to_h4(v);
        } else if (i4 < ENC_F4) {
            int j = i4 - N_NODES * 16;
            int row = j >> 4, fq = j & 15;
            f4 w0 = *(const f4*)(We + fq * 4);
            f4 w1 = *(const f4*)(We + HD + fq * 4);
            f4 bev = *(const f4*)(be + fq * 4);
            float x0 = edge_x[2 * row], x1 = edge_x[2 * row + 1];
            f4 v;
#pragma unroll
            for (int c = 0; c < 4; c++) v[c] = fmaxf(x0 * w0[c] + x1 * w1[c] + bev[c], 0.f);
            *(h4*)(xeH + (long)j * 4) = f4_to_h4(v);
        }
        return;
    }
    int side = (int)blockIdx.x >= TPS;
    int lb = blockIdx.x - (side ? TPS : 0);
    const int* dsts = side ? e2n_dst : n2e_dst;
    const int* srcs = side ? e2n_src : n2e_src;
    int NB = side ? NB_NB : EB_NB;
    int SH = side ? NB_SH : EB_SH;
    int CAP = side ? NB_CAP : EB_CAP;
    int* bins = side ? binN : binE;
    int* gcnt = side ? gcntN : gcntE;
    int base = lb * TILE;

    hist[t] = 0;
    __syncthreads();

    int pair[16], buck[16];
#pragma unroll
    for (int k = 0; k < 16; k++) {
        int e = base + k * 256 + t;
        if (e < N_EDGES) {
            int d = dsts[e];
            int s = srcs[e];
            buck[k] = d >> SH;
            pair[k] = ((d & ((1 << SH) - 1)) << 17) | s;
            atomicAdd(&hist[buck[k]], 1);
        } else buck[k] = -1;
    }
    __syncthreads();
    int v = hist[t];
    scanv[t] = v;
    __syncthreads();
    for (int o = 1; o < 256; o <<= 1) {
        int x = (t >= o) ? scanv[t - o] : 0;
        __syncthreads();
        scanv[t] += x;
        __syncthreads();
    }
    start[t] = scanv[t] - v;
    curs[t] = scanv[t] - v;
    if (t < NB && v > 0) gbase[t] = t * CAP + atomicAdd(&gcnt[t], v);
    __syncthreads();
    int total = scanv[255];
#pragma unroll
    for (int k = 0; k < 16; k++) {
        if (buck[k] >= 0) {
            int slot = atomicAdd(&curs[buck[k]], 1);
            pairsL[slot] = pair[k];
        }
    }
    __syncthreads();
    for (int i = t; i < total; i += 256) {
        int lo = 0, hi = NB - 1;
        while (lo < hi) { int mid = (lo + hi + 1) >> 1; if (start[mid] <= i) lo = mid; else hi = mid - 1; }
        bins[gbase[lo] + (i - start[lo])] = pairsL[i];
    }
}

// ---------------- pass 2: per-bucket fine CSR fill (E-side u32 src, N-side u16 src) ----------------
__global__ __launch_bounds__(512) void fine_fill(
    const int* __restrict__ binE, const int* __restrict__ binN,
    const int* __restrict__ gcntE, const int* __restrict__ gcntN,
    int* __restrict__ off, int* __restrict__ deg,
    int* __restrict__ srtE, unsigned short* __restrict__ srtN) {
    __shared__ int hist[512], scanv[512];
    int t = threadIdx.x;
    int side = (int)blockIdx.x >= EB_NB;
    int b = blockIdx.x - (side ? EB_NB : 0);
    int NROWS = side ? 512 : 256;
    int CAP = side ? NB_CAP : EB_CAP;
    const int* bins = (side ? binN : binE) + (long)b * CAP;
    int cnt_b = (side ? gcntN : gcntE)[b];
    int rowbase = side ? (N_HEDGES + b * 512) : b * 256;
    int nrows = (side ? N_NODES : N_HEDGES) - (side ? b * 512 : b * 256);
    if (nrows > NROWS) nrows = NROWS;
    int* srtEb = srtE + (long)b * CAP;
    unsigned short* srtNb = srtN + (long)b * CAP;

    hist[t] = 0;
    __syncthreads();
    for (int i = t; i < cnt_b; i += 512) atomicAdd(&hist[bins[i] >> 17], 1);
    __syncthreads();
    int v = hist[t];
    scanv[t] = v;
    __syncthreads();
    for (int o = 1; o < 512; o <<= 1) {
        int x = (t >= o) ? scanv[t - o] : 0;
        __syncthreads();
        scanv[t] += x;
        __syncthreads();
    }
    int excl = scanv[t] - v;
    if (t < nrows) { off[rowbase + t] = b * CAP + excl; deg[rowbase + t] = v; }
    scanv[t] = excl;
    __syncthreads();
    for (int i = t; i < cnt_b; i += 512) {
        int p = bins[i];
        int pos = atomicAdd(&scanv[p >> 17], 1);
        if (side) srtNb[pos] = (unsigned short)(p & 0x1FFFF);  // hyperedge ids < 25000
        else srtEb[pos] = p & 0x1FFFF;                         // node ids < 100000
    }
}

// ---------------- gather-mean f16, packed-f16 accumulation (round-9 lane structure) ----------------
__global__ __launch_bounds__(256) void gather_layer(
    const _Float16* __restrict__ xnH, const _Float16* __restrict__ xeH,
    const int* __restrict__ off, const int* __restrict__ deg,
    const int* __restrict__ srtE, const unsigned short* __restrict__ srtN,
    _Float16* __restrict__ aggEH, _Float16* __restrict__ aggNH) {
    int lane = threadIdx.x & 63;
    int w = blockIdx.x * 4 + (threadIdx.x >> 6);
    int NW = gridDim.x * 4;
    int esub = lane >> 4;   // 0..3: edge sublane
    int fq = lane & 15;     // h4 chunk
    const int RT = N_HEDGES + N_NODES;
    for (int r = w; r < RT; r += NW) {
        const _Float16* xsrc; _Float16* agg; int rr;
        bool eSide = r < N_HEDGES;
        if (eSide) { rr = r; xsrc = xnH; agg = aggEH; }
        else { rr = r - N_HEDGES; xsrc = xeH; agg = aggNH; }
        int lo = off[r];
        int dg = deg[r];
        h4 a0 = {(_Float16)0.f, (_Float16)0.f, (_Float16)0.f, (_Float16)0.f};
        h4 a1 = a0;
        for (int j0 = 0; j0 < dg; j0 += 64) {
            int chunk = dg - j0;
            if (chunk > 64) chunk = 64;
            int idv;
            if (eSide) idv = (j0 + lane < dg) ? srtE[lo + j0 + lane] : 0;
            else idv = (j0 + lane < dg) ? (int)srtN[lo + j0 + lane] : 0;
            int jj = 0;
            for (; jj + 8 <= chunk; jj += 8) {
                int s0 = __shfl(idv, jj + esub);
                int s1 = __shfl(idv, jj + 4 + esub);
                h4 h0 = ((const h4*)(xsrc + (long)s0 * HD))[fq];
                h4 h1 = ((const h4*)(xsrc + (long)s1 * HD))[fq];
                a0 += h0;   // 2x v_pk_add_f16
                a1 += h1;
            }
            for (; jj < chunk; jj += 4) {
                int e = jj + esub;
                int s = __shfl(idv, e & 63);
                h4 h = ((const h4*)(xsrc + (long)s * HD))[fq];
                if (e < chunk) a0 += h;
            }
        }
        a0 += a1;
        // butterfly reduce across the 4 edge-sublanes (packed f16 via 32-bit shuffles)
#pragma unroll
        for (int m = 16; m <= 32; m <<= 1) {
            i2 wv = __builtin_bit_cast(i2, a0);
            wv.x = __shfl_xor(wv.x, m);
            wv.y = __shfl_xor(wv.y, m);
            a0 += __builtin_bit_cast(h4, wv);
        }
        if (lane < 16) {
            float invd = 1.f / (float)(dg > 1 ? dg : 1);
            _Float16 ih = (_Float16)invd;
            h4 o = a0;
            o[0] *= ih; o[1] *= ih; o[2] *= ih; o[3] *= ih;  // 2x v_pk_mul_f16
            *(h4*)(agg + (long)rr * HD + fq * 4) = o;
        }
    }
}

// ---------------- combine via MFMA f16: out = relu([agg|xdst] @ [Wl;Wr] + bl) ----------------
__global__ __launch_bounds__(256) void combine_mfma(
    const _Float16* __restrict__ aggEH, const _Float16* __restrict__ xeH,
    const _Float16* __restrict__ aggNH, const _Float16* __restrict__ xnH,
    const _Float16* __restrict__ WtE, const float* __restrict__ blE,
    const _Float16* __restrict__ WtN, const float* __restrict__ blN,
    _Float16* __restrict__ outEH, _Float16* __restrict__ outNH, int gbE) {
    __shared__ _Float16 sA[64][136];
    __shared__ _Float16 sW[64][136];
    int t = threadIdx.x;
    const _Float16 *aggH, *xdstH, *Wt;
    const float* bl;
    _Float16* outH;
    int rows, row0;
    if ((int)blockIdx.x < gbE) {
        aggH = aggEH; xdstH = xeH; Wt = WtE; bl = blE; outH = outEH;
        rows = N_HEDGES; row0 = blockIdx.x * 64;
    } else {
        aggH = aggNH; xdstH = xnH; Wt = WtN; bl = blN; outH = outNH;
        rows = N_NODES; row0 = (blockIdx.x - gbE) * 64;
    }

#pragma unroll
    for (int q = 0; q < 4; q++) {
        int idx = q * 256 + t;
        int c = idx >> 4, ch = idx & 15;
        *(h8*)&sW[c][ch * 8] = *(const h8*)(Wt + c * 128 + ch * 8);
    }
#pragma unroll
    for (int q = 0; q < 4; q++) {
        int idx = q * 256 + t;
        int r = idx >> 4, ch = idx & 15;
        int gr = row0 + r;
        h8 v;
        if (gr < rows) {
            v = (ch < 8) ? *(const h8*)(aggH + (long)gr * HD + ch * 8)
                         : *(const h8*)(xdstH + (long)gr * HD + (ch - 8) * 8);
        } else {
            v = (h8){(_Float16)0.f, (_Float16)0.f, (_Float16)0.f, (_Float16)0.f,
                     (_Float16)0.f, (_Float16)0.f, (_Float16)0.f, (_Float16)0.f};
        }
        *(h8*)&sA[r][ch * 8] = v;
    }
    __syncthreads();

    int lane = t & 63, w = t >> 6;
    int m0 = w * 16;
    int l15 = lane & 15, quad = lane >> 4;
    f4 acc[4];
#pragma unroll
    for (int ct = 0; ct < 4; ct++) {
        float b = bl[ct * 16 + l15];
        acc[ct] = (f4){b, b, b, b};
    }
#pragma unroll
    for (int kb = 0; kb < 4; kb++) {
        h8 a = *(const h8*)&sA[m0 + l15][kb * 32 + quad * 8];
#pragma unroll
        for (int ct = 0; ct < 4; ct++) {
            h8 bfr = *(const h8*)&sW[ct * 16 + l15][kb * 32 + quad * 8];
            acc[ct] = __builtin_amdgcn_mfma_f32_16x16x32_f16(a, bfr, acc[ct], 0, 0, 0);
        }
    }
#pragma unroll
    for (int ct = 0; ct < 4; ct++) {
#pragma unroll
        for (int r = 0; r < 4; r++) {
            int gr = row0 + m0 + quad * 4 + r;
            if (gr < rows) outH[(long)gr * HD + ct * 16 + l15] = (_Float16)fmaxf(acc[ct][r], 0.f);
        }
    }
}

// ---------------- parallel pooling from f16 feats ----------------
__device__ __forceinline__ int lower_bound_dev(const int* arr, int n, int key) {
    int lo = 0, hi = n;
    while (lo < hi) { int mid = (lo + hi) >> 1; if (arr[mid] < key) lo = mid + 1; else hi = mid; }
    return lo;
}

#define PB_N 8
#define PB_E 2
__global__ __launch_bounds__(256) void pool_bf(
    const _Float16* __restrict__ xnH, const _Float16* __restrict__ xeH,
    const int* __restrict__ node_batch, const int* __restrict__ edge_batch,
    float* __restrict__ poolN, float* __restrict__ poolE) {
    __shared__ float sp[4][64];
    int b = blockIdx.x;
    const _Float16* x; const int* batch; float* pool; int n, g, part, P;
    if (b < NG * PB_N) { x = xnH; batch = node_batch; pool = poolN; n = N_NODES; g = b / PB_N; part = b % PB_N; P = PB_N; }
    else { b -= NG * PB_N; x = xeH; batch = edge_batch; pool = poolE; n = N_HEDGES; g = b / PB_E; part = b % PB_E; P = PB_E; }
    int s = lower_bound_dev(batch, n, g);
    int e = lower_bound_dev(batch, n, g + 1);
    int len = e - s;
    int start = s + (int)(((long)len * part) / P);
    int end = s + (int)(((long)len * (part + 1)) / P);
    int lane = threadIdx.x & 63, w = threadIdx.x >> 6;
    int fq = lane & 7, sub = lane >> 3;
    f4 a0 = {0.f, 0.f, 0.f, 0.f}, a1 = a0;
    for (int r = start + w * 8 + sub; r < end; r += 32) {
        h8 h = *(const h8*)(x + (long)r * HD + fq * 8);
#pragma unroll
        for (int c = 0; c < 4; c++) { a0[c] += (float)h[c]; a1[c] += (float)h[c + 4]; }
    }
#pragma unroll
    for (int c = 0; c < 4; c++) {
        a0[c] += __shfl_xor(a0[c], 8);  a1[c] += __shfl_xor(a1[c], 8);
        a0[c] += __shfl_xor(a0[c], 16); a1[c] += __shfl_xor(a1[c], 16);
        a0[c] += __shfl_xor(a0[c], 32); a1[c] += __shfl_xor(a1[c], 32);
    }
    if (lane < 8) {
        *(f4*)&sp[w][fq * 8] = a0;
        *(f4*)&sp[w][fq * 8 + 4] = a1;
    }
    __syncthreads();
    if (threadIdx.x < 64) {
        int tt = threadIdx.x;
        float v = sp[0][tt] + sp[1][tt] + sp[2][tt] + sp[3][tt];
        if (v != 0.f) atomicAdd(&pool[g * HD + tt], v);
    }
}

// ---------------- final readout (one block per graph) ----------------
__global__ __launch_bounds__(64) void final_readout(
    const float* __restrict__ poolN, const float* __restrict__ poolE,
    const int* __restrict__ node_batch, const int* __restrict__ edge_batch,
    const float* __restrict__ Wout, const float* __restrict__ bout,
    float* __restrict__ out) {
    __shared__ float inv[2];
    int g = blockIdx.x, t = threadIdx.x;
    if (t < 2) {
        const int* arr = t ? edge_batch : node_batch;
        int n = t ? N_HEDGES : N_NODES;
        int lo = lower_bound_dev(arr, n, g);
        int hi = lower_bound_dev(arr, n, g + 1);
        int c = hi - lo;
        inv[t] = 1.f / (float)(c > 1 ? c : 1);
    }
    __syncthreads();
    if (t < 32) {
        float iN = inv[0], iE = inv[1];
        float s = bout[t];
#pragma unroll 8
        for (int k = 0; k < HD; k++)
            s += poolN[g * HD + k] * iN * Wout[k * 32 + t]
               + poolE[g * HD + k] * iE * Wout[(HD + k) * 32 + t];
        out[g * 32 + t] = s;
    }
}

extern "C" void kernel_launch(void* const* d_in, const int* in_sizes, int n_in,
                              void* d_out, int out_size, void* d_ws, size_t ws_size,
                              hipStream_t stream) {
    const float* node_x = (const float*)d_in[0];
    const float* edge_x = (const float*)d_in[1];
    const int* n2e_src = (const int*)d_in[2];
    const int* n2e_dst = (const int*)d_in[3];
    const int* e2n_src = (const int*)d_in[4];
    const int* e2n_dst = (const int*)d_in[5];
    const int* node_batch = (const int*)d_in[6];
    const int* edge_batch = (const int*)d_in[7];
    const float* Wn = (const float*)d_in[8];
    const float* bn = (const float*)d_in[9];
    const float* We = (const float*)d_in[10];
    const float* be = (const float*)d_in[11];
    const float* W1l_n2e = (const float*)d_in[12];
    const float* b1l_n2e = (const float*)d_in[13];
    const float* W1r_n2e = (const float*)d_in[14];
    const float* W1l_e2n = (const float*)d_in[15];
    const float* b1l_e2n = (const float*)d_in[16];
    const float* W1r_e2n = (const float*)d_in[17];
    const float* W2l_n2e = (const float*)d_in[18];
    const float* b2l_n2e = (const float*)d_in[19];
    const float* W2r_n2e = (const float*)d_in[20];
    const float* W2l_e2n = (const float*)d_in[21];
    const float* b2l_e2n = (const float*)d_in[22];
    const float* W2r_e2n = (const float*)d_in[23];
    const float* Wout = (const float*)d_in[24];
    const float* bout = (const float*)d_in[25];
    float* out = (float*)d_out;

    // ---- workspace layout (row-major f16 features) ----
    _Float16* AH0 = (_Float16*)d_ws;              // 6.4M: xn f16 -> xn2
    _Float16* BH0 = AH0 + N_NODES * HD;           // 1.6M: xe -> xe2
    _Float16* AH1 = BH0 + N_HEDGES * HD;          // 6.4M: xn1
    _Float16* BH1 = AH1 + N_NODES * HD;           // 1.6M: xe1
    _Float16* aggNH = BH1 + N_HEDGES * HD;        // 6.4M
    _Float16* aggEH = aggNH + N_NODES * HD;       // 1.6M
    _Float16* WtH = aggEH + N_HEDGES * HD;        // 32768 (4 x [64][128])
    float* poolN = (float*)(WtH + 4 * 8192);      // 4096
    float* poolE = poolN + NG * HD;               // 4096
    int* gcntE = (int*)(poolE + NG * HD);         // 98
    int* gcntN = gcntE + EB_NB;                   // 196
    int* off = gcntN + NB_NB;                     // 125000
    int* deg = off + (N_HEDGES + N_NODES);        // 125000
    int* binE = deg + (N_HEDGES + N_NODES);       // 1,176,000
    int* binN = binE + EB_NB * EB_CAP;            // 1,215,200
    int* srtE = binN + NB_NB * NB_CAP;            // 1,176,000 u32
    unsigned short* srtN = (unsigned short*)(srtE + EB_NB * EB_CAP);  // 1,215,200 u16

    const int Bt = 256;

    // 1) prep: Wt conversion + zero pools/cursors (contiguous: poolN..gcntN)
    int zn = 2 * NG * HD + EB_NB + NB_NB;
    prep<<<4 + (zn + Bt - 1) / Bt, Bt, 0, stream>>>(
        W1l_n2e, W1r_n2e, W1l_e2n, W1r_e2n,
        W2l_n2e, W2r_n2e, W2l_e2n, W2r_e2n,
        WtH, (int*)poolN, zn);

    // 2) binning + encoder
    int encBlocks = (ENC_F4 + Bt - 1) / Bt;
    bin_encode<<<2 * TPS + encBlocks, Bt, 0, stream>>>(
        n2e_src, n2e_dst, e2n_src, e2n_dst, binE, binN, gcntE, gcntN,
        node_x, edge_x, Wn, bn, We, be, AH0, BH0);

    // 3) fine CSR fill
    fine_fill<<<EB_NB + NB_NB, 512, 0, stream>>>(binE, binN, gcntE, gcntN,
                                                 off, deg, srtE, srtN);

    int gbE = (N_HEDGES + 63) / 64;  // 391
    int gbN = (N_NODES + 63) / 64;   // 1563
    int gridC = gbE + gbN;

    // 4-5) layer 1
    gather_layer<<<2048, Bt, 0, stream>>>(AH0, BH0, off, deg, srtE, srtN, aggEH, aggNH);
    combine_mfma<<<gridC, Bt, 0, stream>>>(aggEH, BH0, aggNH, AH0,
                                           WtH, b1l_n2e, WtH + 8192, b1l_e2n,
                                           BH1, AH1, gbE);

    // 6-7) layer 2
    gather_layer<<<2048, Bt, 0, stream>>>(AH1, BH1, off, deg, srtE, srtN, aggEH, aggNH);
    combine_mfma<<<gridC, Bt, 0, stream>>>(aggEH, BH1, aggNH, AH1,
                                           WtH + 16384, b2l_n2e, WtH + 24576, b2l_e2n,
                                           BH0, AH0, gbE);

    // 8) pooling
    pool_bf<<<NG * PB_N + NG * PB_E, Bt, 0, stream>>>(AH0, BH0, node_batch, edge_batch, poolN, poolE);

    // 9) readout
    final_readout<<<NG, 64, 0, stream>>>(poolN, poolE, node_batch, edge_batch, Wout, bout, out);
}

// Round 14
// 183.953 us; speedup vs baseline: 1.2152x; 1.0005x over previous
//
#include <hip/hip_runtime.h>

#define N_NODES 100000
#define N_HEDGES 25000
#define N_EDGES 1000000
#define NG 64
#define HD 64

// binned CSR build params
#define EB_SH 8
#define EB_NB 98
#define EB_CAP 12000
#define NB_SH 9
#define NB_NB 196
#define NB_CAP 6200
#define TILE 4096
#define TPS 245
#define ENC_F4 ((N_NODES + N_HEDGES) * 16)

typedef __attribute__((ext_vector_type(4))) float f4;
typedef __attribute__((ext_vector_type(4))) _Float16 h4;
typedef __attribute__((ext_vector_type(8))) _Float16 h8;
typedef __attribute__((ext_vector_type(2))) int i2;

__device__ __forceinline__ h4 f4_to_h4(f4 v) {
    h4 o;
    o[0] = (_Float16)v[0]; o[1] = (_Float16)v[1];
    o[2] = (_Float16)v[2]; o[3] = (_Float16)v[3];
    return o;
}

// ---------------- prep: W->Wt f16 transpose (blocks 0-3) + zero (rest) ----------------
__global__ __launch_bounds__(256) void prep(
    const float* __restrict__ W1lE, const float* __restrict__ W1rE,
    const float* __restrict__ W1lN, const float* __restrict__ W1rN,
    const float* __restrict__ W2lE, const float* __restrict__ W2rE,
    const float* __restrict__ W2lN, const float* __restrict__ W2rN,
    _Float16* __restrict__ WtH, int* __restrict__ zbase, int zn) {
    int b = blockIdx.x, t = threadIdx.x;
    if (b < 4) {
        const float *Wl, *Wr;
        switch (b) {
            case 0: Wl = W1lE; Wr = W1rE; break;
            case 1: Wl = W1lN; Wr = W1rN; break;
            case 2: Wl = W2lE; Wr = W2rE; break;
            default: Wl = W2lN; Wr = W2rN; break;
        }
        _Float16* o = WtH + b * 8192;
        for (int idx = t; idx < 8192; idx += 256) {
            int c = idx >> 7, k = idx & 127;
            float v = (k < 64) ? Wl[k * 64 + c] : Wr[(k - 64) * 64 + c];
            o[c * 128 + k] = (_Float16)v;  // Wt[col][k]: B^T layout
        }
    } else {
        int i = (b - 4) * 256 + t;
        if (i < zn) zbase[i] = 0;
    }
}

// ---------------- pass 1: LDS-binned scatter + fused encoder (row-major f16 out) ----------------
__global__ __launch_bounds__(256) void bin_encode(
    const int* __restrict__ n2e_src, const int* __restrict__ n2e_dst,
    const int* __restrict__ e2n_src, const int* __restrict__ e2n_dst,
    int* __restrict__ binE, int* __restrict__ binN,
    int* __restrict__ gcntE, int* __restrict__ gcntN,
    const float* __restrict__ node_x, const float* __restrict__ edge_x,
    const float* __restrict__ Wn, const float* __restrict__ bn,
    const float* __restrict__ We, const float* __restrict__ be,
    _Float16* __restrict__ xnH, _Float16* __restrict__ xeH) {
    __shared__ int pairsL[TILE];
    __shared__ int hist[256], scanv[256], start[256], curs[256], gbase[256];
    int t = threadIdx.x;
    if ((int)blockIdx.x >= 2 * TPS) {
        int i4 = ((int)blockIdx.x - 2 * TPS) * 256 + t;
        if (i4 < N_NODES * 16) {
            int row = i4 >> 4, fq = i4 & 15;
            f4 wn = *(const f4*)(Wn + fq * 4);
            f4 bnv = *(const f4*)(bn + fq * 4);
            float xv = node_x[row];
            f4 v;
#pragma unroll
            for (int c = 0; c < 4; c++) v[c] = fmaxf(xv * wn[c] + bnv[c], 0.f);
            *(h4*)(xnH + (long)i4 * 4) = f4_to_h4(v);
        } else if (i4 < ENC_F4) {
            int j = i4 - N_NODES * 16;
            int row = j >> 4, fq = j & 15;
            f4 w0 = *(const f4*)(We + fq * 4);
            f4 w1 = *(const f4*)(We + HD + fq * 4);
            f4 bev = *(const f4*)(be + fq * 4);
            float x0 = edge_x[2 * row], x1 = edge_x[2 * row + 1];
            f4 v;
#pragma unroll
            for (int c = 0; c < 4; c++) v[c] = fmaxf(x0 * w0[c] + x1 * w1[c] + bev[c], 0.f);
            *(h4*)(xeH + (long)j * 4) = f4_to_h4(v);
        }
        return;
    }
    int side = (int)blockIdx.x >= TPS;
    int lb = blockIdx.x - (side ? TPS : 0);
    const int* dsts = side ? e2n_dst : n2e_dst;
    const int* srcs = side ? e2n_src : n2e_src;
    int NB = side ? NB_NB : EB_NB;
    int SH = side ? NB_SH : EB_SH;
    int CAP = side ? NB_CAP : EB_CAP;
    int* bins = side ? binN : binE;
    int* gcnt = side ? gcntN : gcntE;
    int base = lb * TILE;

    hist[t] = 0;
    __syncthreads();

    int pair[16], buck[16];
#pragma unroll
    for (int k = 0; k < 16; k++) {
        int e = base + k * 256 + t;
        if (e < N_EDGES) {
            int d = dsts[e];
            int s = srcs[e];
            buck[k] = d >> SH;
            pair[k] = ((d & ((1 << SH) - 1)) << 17) | s;
            atomicAdd(&hist[buck[k]], 1);
        } else buck[k] = -1;
    }
    __syncthreads();
    int v = hist[t];
    scanv[t] = v;
    __syncthreads();
    for (int o = 1; o < 256; o <<= 1) {
        int x = (t >= o) ? scanv[t - o] : 0;
        __syncthreads();
        scanv[t] += x;
        __syncthreads();
    }
    start[t] = scanv[t] - v;
    curs[t] = scanv[t] - v;
    if (t < NB && v > 0) gbase[t] = t * CAP + atomicAdd(&gcnt[t], v);
    __syncthreads();
    int total = scanv[255];
#pragma unroll
    for (int k = 0; k < 16; k++) {
        if (buck[k] >= 0) {
            int slot = atomicAdd(&curs[buck[k]], 1);
            pairsL[slot] = pair[k];
        }
    }
    __syncthreads();
    for (int i = t; i < total; i += 256) {
        int lo = 0, hi = NB - 1;
        while (lo < hi) { int mid = (lo + hi + 1) >> 1; if (start[mid] <= i) lo = mid; else hi = mid - 1; }
        bins[gbase[lo] + (i - start[lo])] = pairsL[i];
    }
}

// ---------------- pass 2: per-bucket fine CSR fill, single global pass (LDS bin staging) ----------------
__global__ __launch_bounds__(512) void fine_fill(
    const int* __restrict__ binE, const int* __restrict__ binN,
    const int* __restrict__ gcntE, const int* __restrict__ gcntN,
    int* __restrict__ off, int* __restrict__ deg,
    int* __restrict__ srtE, unsigned short* __restrict__ srtN) {
    __shared__ int hist[512], scanv[512];
    __shared__ int binsL[EB_CAP];  // 48 KB; N-side cnt <= NB_CAP < EB_CAP
    int t = threadIdx.x;
    int side = (int)blockIdx.x >= EB_NB;
    int b = blockIdx.x - (side ? EB_NB : 0);
    int NROWS = side ? 512 : 256;
    int CAP = side ? NB_CAP : EB_CAP;
    const int* bins = (side ? binN : binE) + (long)b * CAP;
    int cnt_b = (side ? gcntN : gcntE)[b];
    int rowbase = side ? (N_HEDGES + b * 512) : b * 256;
    int nrows = (side ? N_NODES : N_HEDGES) - (side ? b * 512 : b * 256);
    if (nrows > NROWS) nrows = NROWS;
    int* srtEb = srtE + (long)b * CAP;
    unsigned short* srtNb = srtN + (long)b * CAP;

    hist[t] = 0;
    for (int i = t; i < cnt_b; i += 512) binsL[i] = bins[i];  // one coalesced global read
    __syncthreads();
    for (int i = t; i < cnt_b; i += 512) atomicAdd(&hist[binsL[i] >> 17], 1);
    __syncthreads();
    int v = hist[t];
    scanv[t] = v;
    __syncthreads();
    for (int o = 1; o < 512; o <<= 1) {
        int x = (t >= o) ? scanv[t - o] : 0;
        __syncthreads();
        scanv[t] += x;
        __syncthreads();
    }
    int excl = scanv[t] - v;
    if (t < nrows) { off[rowbase + t] = b * CAP + excl; deg[rowbase + t] = v; }
    scanv[t] = excl;
    __syncthreads();
    for (int i = t; i < cnt_b; i += 512) {
        int p = binsL[i];
        int pos = atomicAdd(&scanv[p >> 17], 1);
        if (side) srtNb[pos] = (unsigned short)(p & 0x1FFFF);  // hyperedge ids < 25000
        else srtEb[pos] = p & 0x1FFFF;                         // node ids < 100000
    }
}

// ---------------- gather-mean f16: pre-shifted byte-offset indices, packed-f16 accumulation ----------------
__global__ __launch_bounds__(256) void gather_layer(
    const _Float16* __restrict__ xnH, const _Float16* __restrict__ xeH,
    const int* __restrict__ off, const int* __restrict__ deg,
    const int* __restrict__ srtE, const unsigned short* __restrict__ srtN,
    _Float16* __restrict__ aggEH, _Float16* __restrict__ aggNH) {
    int lane = threadIdx.x & 63;
    int w = blockIdx.x * 4 + (threadIdx.x >> 6);
    int NW = gridDim.x * 4;
    int esub = lane >> 4;   // 0..3: edge sublane
    int fq = lane & 15;     // h4 chunk
    int fq8 = fq * 8;       // byte offset of this lane's h4 within a row
    const int RT = N_HEDGES + N_NODES;
    for (int r = w; r < RT; r += NW) {
        const char* xsrcB; _Float16* agg; int rr;
        bool eSide = r < N_HEDGES;
        if (eSide) { rr = r; xsrcB = (const char*)xnH; agg = aggEH; }
        else { rr = r - N_HEDGES; xsrcB = (const char*)xeH; agg = aggNH; }
        int lo = off[r];
        int dg = deg[r];
        h4 a0 = {(_Float16)0.f, (_Float16)0.f, (_Float16)0.f, (_Float16)0.f};
        h4 a1 = a0;
        for (int j0 = 0; j0 < dg; j0 += 64) {
            int chunk = dg - j0;
            if (chunk > 64) chunk = 64;
            int idv;
            if (eSide) idv = (j0 + lane < dg) ? srtE[lo + j0 + lane] : 0;
            else idv = (j0 + lane < dg) ? (int)srtN[lo + j0 + lane] : 0;
            idv <<= 7;  // row id -> byte offset (128 B/row); shuffles now carry byte offsets
            int jj = 0;
            for (; jj + 8 <= chunk; jj += 8) {
                int b0 = __shfl(idv, jj + esub) + fq8;
                int b1 = __shfl(idv, jj + 4 + esub) + fq8;
                h4 h0 = *(const h4*)(xsrcB + b0);
                h4 h1 = *(const h4*)(xsrcB + b1);
                a0 += h0;   // v_pk_add_f16 x2
                a1 += h1;
            }
            for (; jj < chunk; jj += 4) {
                int e = jj + esub;
                int b0 = __shfl(idv, e & 63) + fq8;
                h4 h = *(const h4*)(xsrcB + b0);
                if (e < chunk) a0 += h;
            }
        }
        a0 += a1;
        // butterfly reduce across the 4 edge-sublanes (packed f16 via 32-bit shuffles)
#pragma unroll
        for (int m = 16; m <= 32; m <<= 1) {
            i2 wv = __builtin_bit_cast(i2, a0);
            wv.x = __shfl_xor(wv.x, m);
            wv.y = __shfl_xor(wv.y, m);
            a0 += __builtin_bit_cast(h4, wv);
        }
        if (lane < 16) {
            float invd = 1.f / (float)(dg > 1 ? dg : 1);
            _Float16 ih = (_Float16)invd;
            h4 o = a0;
            o[0] *= ih; o[1] *= ih; o[2] *= ih; o[3] *= ih;  // v_pk_mul_f16 x2
            *(h4*)(agg + (long)rr * HD + fq * 4) = o;
        }
    }
}

// ---------------- combine via MFMA f16: out = relu([agg|xdst] @ [Wl;Wr] + bl) ----------------
__global__ __launch_bounds__(256) void combine_mfma(
    const _Float16* __restrict__ aggEH, const _Float16* __restrict__ xeH,
    const _Float16* __restrict__ aggNH, const _Float16* __restrict__ xnH,
    const _Float16* __restrict__ WtE, const float* __restrict__ blE,
    const _Float16* __restrict__ WtN, const float* __restrict__ blN,
    _Float16* __restrict__ outEH, _Float16* __restrict__ outNH, int gbE) {
    __shared__ _Float16 sA[64][136];
    __shared__ _Float16 sW[64][136];
    int t = threadIdx.x;
    const _Float16 *aggH, *xdstH, *Wt;
    const float* bl;
    _Float16* outH;
    int rows, row0;
    if ((int)blockIdx.x < gbE) {
        aggH = aggEH; xdstH = xeH; Wt = WtE; bl = blE; outH = outEH;
        rows = N_HEDGES; row0 = blockIdx.x * 64;
    } else {
        aggH = aggNH; xdstH = xnH; Wt = WtN; bl = blN; outH = outNH;
        rows = N_NODES; row0 = (blockIdx.x - gbE) * 64;
    }

#pragma unroll
    for (int q = 0; q < 4; q++) {
        int idx = q * 256 + t;
        int c = idx >> 4, ch = idx & 15;
        *(h8*)&sW[c][ch * 8] = *(const h8*)(Wt + c * 128 + ch * 8);
    }
#pragma unroll
    for (int q = 0; q < 4; q++) {
        int idx = q * 256 + t;
        int r = idx >> 4, ch = idx & 15;
        int gr = row0 + r;
        h8 v;
        if (gr < rows) {
            v = (ch < 8) ? *(const h8*)(aggH + (long)gr * HD + ch * 8)
                         : *(const h8*)(xdstH + (long)gr * HD + (ch - 8) * 8);
        } else {
            v = (h8){(_Float16)0.f, (_Float16)0.f, (_Float16)0.f, (_Float16)0.f,
                     (_Float16)0.f, (_Float16)0.f, (_Float16)0.f, (_Float16)0.f};
        }
        *(h8*)&sA[r][ch * 8] = v;
    }
    __syncthreads();

    int lane = t & 63, w = t >> 6;
    int m0 = w * 16;
    int l15 = lane & 15, quad = lane >> 4;
    f4 acc[4];
#pragma unroll
    for (int ct = 0; ct < 4; ct++) {
        float b = bl[ct * 16 + l15];
        acc[ct] = (f4){b, b, b, b};
    }
#pragma unroll
    for (int kb = 0; kb < 4; kb++) {
        h8 a = *(const h8*)&sA[m0 + l15][kb * 32 + quad * 8];
#pragma unroll
        for (int ct = 0; ct < 4; ct++) {
            h8 bfr = *(const h8*)&sW[ct * 16 + l15][kb * 32 + quad * 8];
            acc[ct] = __builtin_amdgcn_mfma_f32_16x16x32_f16(a, bfr, acc[ct], 0, 0, 0);
        }
    }
#pragma unroll
    for (int ct = 0; ct < 4; ct++) {
#pragma unroll
        for (int r = 0; r < 4; r++) {
            int gr = row0 + m0 + quad * 4 + r;
            if (gr < rows) outH[(long)gr * HD + ct * 16 + l15] = (_Float16)fmaxf(acc[ct][r], 0.f);
        }
    }
}

// ---------------- parallel pooling from f16 feats ----------------
__device__ __forceinline__ int lower_bound_dev(const int* arr, int n, int key) {
    int lo = 0, hi = n;
    while (lo < hi) { int mid = (lo + hi) >> 1; if (arr[mid] < key) lo = mid + 1; else hi = mid; }
    return lo;
}

#define PB_N 8
#define PB_E 2
__global__ __launch_bounds__(256) void pool_bf(
    const _Float16* __restrict__ xnH, const _Float16* __restrict__ xeH,
    const int* __restrict__ node_batch, const int* __restrict__ edge_batch,
    float* __restrict__ poolN, float* __restrict__ poolE) {
    __shared__ float sp[4][64];
    int b = blockIdx.x;
    const _Float16* x; const int* batch; float* pool; int n, g, part, P;
    if (b < NG * PB_N) { x = xnH; batch = node_batch; pool = poolN; n = N_NODES; g = b / PB_N; part = b % PB_N; P = PB_N; }
    else { b -= NG * PB_N; x = xeH; batch = edge_batch; pool = poolE; n = N_HEDGES; g = b / PB_E; part = b % PB_E; P = PB_E; }
    int s = lower_bound_dev(batch, n, g);
    int e = lower_bound_dev(batch, n, g + 1);
    int len = e - s;
    int start = s + (int)(((long)len * part) / P);
    int end = s + (int)(((long)len * (part + 1)) / P);
    int lane = threadIdx.x & 63, w = threadIdx.x >> 6;
    int fq = lane & 7, sub = lane >> 3;
    f4 a0 = {0.f, 0.f, 0.f, 0.f}, a1 = a0;
    for (int r = start + w * 8 + sub; r < end; r += 32) {
        h8 h = *(const h8*)(x + (long)r * HD + fq * 8);
#pragma unroll
        for (int c = 0; c < 4; c++) { a0[c] += (float)h[c]; a1[c] += (float)h[c + 4]; }
    }
#pragma unroll
    for (int c = 0; c < 4; c++) {
        a0[c] += __shfl_xor(a0[c], 8);  a1[c] += __shfl_xor(a1[c], 8);
        a0[c] += __shfl_xor(a0[c], 16); a1[c] += __shfl_xor(a1[c], 16);
        a0[c] += __shfl_xor(a0[c], 32); a1[c] += __shfl_xor(a1[c], 32);
    }
    if (lane < 8) {
        *(f4*)&sp[w][fq * 8] = a0;
        *(f4*)&sp[w][fq * 8 + 4] = a1;
    }
    __syncthreads();
    if (threadIdx.x < 64) {
        int tt = threadIdx.x;
        float v = sp[0][tt] + sp[1][tt] + sp[2][tt] + sp[3][tt];
        if (v != 0.f) atomicAdd(&pool[g * HD + tt], v);
    }
}

// ---------------- final readout (one block per graph) ----------------
__global__ __launch_bounds__(64) void final_readout(
    const float* __restrict__ poolN, const float* __restrict__ poolE,
    const int* __restrict__ node_batch, const int* __restrict__ edge_batch,
    const float* __restrict__ Wout, const float* __restrict__ bout,
    float* __restrict__ out) {
    __shared__ float inv[2];
    int g = blockIdx.x, t = threadIdx.x;
    if (t < 2) {
        const int* arr = t ? edge_batch : node_batch;
        int n = t ? N_HEDGES : N_NODES;
        int lo = lower_bound_dev(arr, n, g);
        int hi = lower_bound_dev(arr, n, g + 1);
        int c = hi - lo;
        inv[t] = 1.f / (float)(c > 1 ? c : 1);
    }
    __syncthreads();
    if (t < 32) {
        float iN = inv[0], iE = inv[1];
        float s = bout[t];
#pragma unroll 8
        for (int k = 0; k < HD; k++)
            s += poolN[g * HD + k] * iN * Wout[k * 32 + t]
               + poolE[g * HD + k] * iE * Wout[(HD + k) * 32 + t];
        out[g * 32 + t] = s;
    }
}

extern "C" void kernel_launch(void* const* d_in, const int* in_sizes, int n_in,
                              void* d_out, int out_size, void* d_ws, size_t ws_size,
                              hipStream_t stream) {
    const float* node_x = (const float*)d_in[0];
    const float* edge_x = (const float*)d_in[1];
    const int* n2e_src = (const int*)d_in[2];
    const int* n2e_dst = (const int*)d_in[3];
    const int* e2n_src = (const int*)d_in[4];
    const int* e2n_dst = (const int*)d_in[5];
    const int* node_batch = (const int*)d_in[6];
    const int* edge_batch = (const int*)d_in[7];
    const float* Wn = (const float*)d_in[8];
    const float* bn = (const float*)d_in[9];
    const float* We = (const float*)d_in[10];
    const float* be = (const float*)d_in[11];
    const float* W1l_n2e = (const float*)d_in[12];
    const float* b1l_n2e = (const float*)d_in[13];
    const float* W1r_n2e = (const float*)d_in[14];
    const float* W1l_e2n = (const float*)d_in[15];
    const float* b1l_e2n = (const float*)d_in[16];
    const float* W1r_e2n = (const float*)d_in[17];
    const float* W2l_n2e = (const float*)d_in[18];
    const float* b2l_n2e = (const float*)d_in[19];
    const float* W2r_n2e = (const float*)d_in[20];
    const float* W2l_e2n = (const float*)d_in[21];
    const float* b2l_e2n = (const float*)d_in[22];
    const float* W2r_e2n = (const float*)d_in[23];
    const float* Wout = (const float*)d_in[24];
    const float* bout = (const float*)d_in[25];
    float* out = (float*)d_out;

    // ---- workspace layout (row-major f16 features) ----
    _Float16* AH0 = (_Float16*)d_ws;              // 6.4M: xn f16 -> xn2
    _Float16* BH0 = AH0 + N_NODES * HD;           // 1.6M: xe -> xe2
    _Float16* AH1 = BH0 + N_HEDGES * HD;          // 6.4M: xn1
    _Float16* BH1 = AH1 + N_NODES * HD;           // 1.6M: xe1
    _Float16* aggNH = BH1 + N_HEDGES * HD;        // 6.4M
    _Float16* aggEH = aggNH + N_NODES * HD;       // 1.6M
    _Float16* WtH = aggEH + N_HEDGES * HD;        // 32768 (4 x [64][128])
    float* poolN = (float*)(WtH + 4 * 8192);      // 4096
    float* poolE = poolN + NG * HD;               // 4096
    int* gcntE = (int*)(poolE + NG * HD);         // 98
    int* gcntN = gcntE + EB_NB;                   // 196
    int* off = gcntN + NB_NB;                     // 125000
    int* deg = off + (N_HEDGES + N_NODES);        // 125000
    int* binE = deg + (N_HEDGES + N_NODES);       // 1,176,000
    int* binN = binE + EB_NB * EB_CAP;            // 1,215,200
    int* srtE = binN + NB_NB * NB_CAP;            // 1,176,000 u32
    unsigned short* srtN = (unsigned short*)(srtE + EB_NB * EB_CAP);  // 1,215,200 u16

    const int Bt = 256;

    // 1) prep: Wt conversion + zero pools/cursors (contiguous: poolN..gcntN)
    int zn = 2 * NG * HD + EB_NB + NB_NB;
    prep<<<4 + (zn + Bt - 1) / Bt, Bt, 0, stream>>>(
        W1l_n2e, W1r_n2e, W1l_e2n, W1r_e2n,
        W2l_n2e, W2r_n2e, W2l_e2n, W2r_e2n,
        WtH, (int*)poolN, zn);

    // 2) binning + encoder
    int encBlocks = (ENC_F4 + Bt - 1) / Bt;
    bin_encode<<<2 * TPS + encBlocks, Bt, 0, stream>>>(
        n2e_src, n2e_dst, e2n_src, e2n_dst, binE, binN, gcntE, gcntN,
        node_x, edge_x, Wn, bn, We, be, AH0, BH0);

    // 3) fine CSR fill (single global pass)
    fine_fill<<<EB_NB + NB_NB, 512, 0, stream>>>(binE, binN, gcntE, gcntN,
                                                 off, deg, srtE, srtN);

    int gbE = (N_HEDGES + 63) / 64;  // 391
    int gbN = (N_NODES + 63) / 64;   // 1563
    int gridC = gbE + gbN;

    // 4-5) layer 1
    gather_layer<<<2048, Bt, 0, stream>>>(AH0, BH0, off, deg, srtE, srtN, aggEH, aggNH);
    combine_mfma<<<gridC, Bt, 0, stream>>>(aggEH, BH0, aggNH, AH0,
                                           WtH, b1l_n2e, WtH + 8192, b1l_e2n,
                                           BH1, AH1, gbE);

    // 6-7) layer 2
    gather_layer<<<2048, Bt, 0, stream>>>(AH1, BH1, off, deg, srtE, srtN, aggEH, aggNH);
    combine_mfma<<<gridC, Bt, 0, stream>>>(aggEH, BH1, aggNH, AH1,
                                           WtH + 16384, b2l_n2e, WtH + 24576, b2l_e2n,
                                           BH0, AH0, gbE);

    // 8) pooling
    pool_bf<<<NG * PB_N + NG * PB_E, Bt, 0, stream>>>(AH0, BH0, node_batch, edge_batch, poolN, poolE);

    // 9) readout
    final_readout<<<NG, 64, 0, stream>>>(poolN, poolE, node_batch, edge_batch, Wout, bout, out);
}